// Round 3
// baseline (509.172 us; speedup 1.0000x reference)
//
#include <hip/hip_runtime.h>

#define N 8192
#define F 128
#define NS 8           // j-splits
#define JC (N / NS)    // 1024 j per split
#define CK 32          // j per chunk (one MFMA K)
#define NC (JC / CK)   // 32 chunks
#define ALPHA 0.2f

typedef __attribute__((ext_vector_type(8))) short short8;
typedef __attribute__((ext_vector_type(4))) float f32x4;
typedef unsigned short u16;

__device__ __forceinline__ u16 f2bf(float f) {
    unsigned int u = __float_as_uint(f);
    u += 0x7fff + ((u >> 16) & 1);  // RNE; finite inputs
    return (u16)(u >> 16);
}
__device__ __forceinline__ float bf2f(u16 b) {
    return __uint_as_float(((unsigned int)b) << 16);
}
__device__ __forceinline__ float lrelu(float z) { return fmaxf(z, ALPHA * z); }

// ---------------- K1: h = x@W ; emit hT (bf16, [feature][node]) + ssrc/sdst (fp32) ----------------
__global__ __launch_bounds__(256) void gemm_h(const float* __restrict__ x,
                                              const float* __restrict__ W,
                                              const float* __restrict__ aa,
                                              u16* __restrict__ hT,
                                              float* __restrict__ ssrc,
                                              float* __restrict__ sdst) {
    __shared__ float xs[32 * 128];
    __shared__ float Wsh[32 * 128];
    const int t = threadIdx.x;
    const int i0 = blockIdx.x * 32;
    const int c4 = (t & 31) * 4;
    const int r8 = t >> 5;

#pragma unroll
    for (int p = 0; p < 4; ++p) {
        int rr = p * 8 + r8;
        *(float4*)&xs[rr * 128 + c4] = *(const float4*)&x[(size_t)(i0 + rr) * 128 + c4];
    }

    const int tx = t & 31, ty = t >> 5;
    const int r0 = ty * 4, c0 = tx * 4;
    float acc[4][4] = {};

    for (int kc = 0; kc < 4; ++kc) {
        __syncthreads();
#pragma unroll
        for (int p = 0; p < 4; ++p) {
            int k = p * 8 + r8;
            *(float4*)&Wsh[k * 128 + c4] = *(const float4*)&W[(kc * 32 + k) * 128 + c4];
        }
        __syncthreads();
#pragma unroll 4
        for (int k = 0; k < 32; k += 4) {
            float xr[4][4];
#pragma unroll
            for (int rr = 0; rr < 4; ++rr)
                *(float4*)xr[rr] = *(const float4*)&xs[(r0 + rr) * 128 + kc * 32 + k];
#pragma unroll
            for (int kk = 0; kk < 4; ++kk) {
                float4 wv = *(const float4*)&Wsh[(k + kk) * 128 + c0];
#pragma unroll
                for (int rr = 0; rr < 4; ++rr) {
                    acc[rr][0] += xr[rr][kk] * wv.x;
                    acc[rr][1] += xr[rr][kk] * wv.y;
                    acc[rr][2] += xr[rr][kk] * wv.z;
                    acc[rr][3] += xr[rr][kk] * wv.w;
                }
            }
        }
    }

    // epilogue 1: hT bf16 transposed store (per col, rr-adjacent shorts merge in L2)
#pragma unroll
    for (int rr = 0; rr < 4; ++rr)
#pragma unroll
        for (int cc = 0; cc < 4; ++cc)
            hT[(size_t)(c0 + cc) * N + (i0 + r0 + rr)] = f2bf(acc[rr][cc]);

    // epilogue 2: fused scores from full-precision accumulators
    float4 asv = *(const float4*)&aa[c0];
    float4 adv = *(const float4*)&aa[F + c0];
#pragma unroll
    for (int rr = 0; rr < 4; ++rr) {
        float vs = acc[rr][0] * asv.x + acc[rr][1] * asv.y + acc[rr][2] * asv.z + acc[rr][3] * asv.w;
        float vd = acc[rr][0] * adv.x + acc[rr][1] * adv.y + acc[rr][2] * adv.z + acc[rr][3] * adv.w;
#pragma unroll
        for (int off = 16; off >= 1; off >>= 1) {
            vs += __shfl_down(vs, off, 32);
            vd += __shfl_down(vd, off, 32);
        }
        if (tx == 0) {
            ssrc[i0 + r0 + rr] = vs;
            sdst[i0 + r0 + rr] = vd;
        }
    }
}

// ---------------- K2: attention, barrier-free. One wave = 16 rows x one j-split. ----------------
// Wave computes its own A-frag (w values) from adj regs; loads B-frags (hT, L2-hot) for all
// 8 col-groups. No LDS, no __syncthreads, depth-2 adj prefetch never drained.
__global__ __launch_bounds__(256, 4) void attn_mfma(const int* __restrict__ adj,
                                                    const u16* __restrict__ hT,
                                                    const float* __restrict__ ssrc,
                                                    const float* __restrict__ sdst,
                                                    float* __restrict__ pacc,
                                                    float* __restrict__ pS) {
    const int t = threadIdx.x;
    const int w = t >> 6, L = t & 63;
    const int quad = L >> 4, l16 = L & 15;
    const int i0 = blockIdx.x * 64 + w * 16;
    const int split = blockIdx.y;
    const int jbase = split * JC;

    const int row = i0 + l16;
    const float s_i = ssrc[row];
    const int* pA = adj + (size_t)row * N + jbase + quad * 8;
    const float* pD = sdst + jbase + quad * 8;
    const u16* pB = hT + (size_t)l16 * N + jbase + quad * 8;

    f32x4 acc[8];
#pragma unroll
    for (int cg = 0; cg < 8; ++cg) acc[cg] = 0.f;
    float rsum = 0.f;

    // depth-2 rotating prefetch regs for adj/sdst
    int4 aj[2][2];
    float4 sd[2][2];
    aj[0][0] = *(const int4*)(pA);
    aj[0][1] = *(const int4*)(pA + 4);
    sd[0][0] = *(const float4*)(pD);
    sd[0][1] = *(const float4*)(pD + 4);
    aj[1][0] = *(const int4*)(pA + CK);
    aj[1][1] = *(const int4*)(pA + CK + 4);
    sd[1][0] = *(const float4*)(pD + CK);
    sd[1][1] = *(const float4*)(pD + CK + 4);

#pragma unroll 2
    for (int c = 0; c < NC; ++c) {
        const int s = c & 1;
        const int off = c * CK;

        // B loads for chunk c, first half (col-groups 0..3)
        short8 B0[4];
#pragma unroll
        for (int cg = 0; cg < 4; ++cg)
            B0[cg] = *(const short8*)(pB + (size_t)cg * 16 * N + off);

        // compute w-frag for chunk c from regs prefetched 2 iters ago
        short8 wf;
        {
            int m[8] = {aj[s][0].x, aj[s][0].y, aj[s][0].z, aj[s][0].w,
                        aj[s][1].x, aj[s][1].y, aj[s][1].z, aj[s][1].w};
            float d[8] = {sd[s][0].x, sd[s][0].y, sd[s][0].z, sd[s][0].w,
                          sd[s][1].x, sd[s][1].y, sd[s][1].z, sd[s][1].w};
#pragma unroll
            for (int k = 0; k < 8; ++k) {
                float e = __expf(lrelu(s_i + d[k]));
                float wv = (m[k] > 0) ? e : 0.f;
                u16 b = f2bf(wv);
                rsum += bf2f(b);
                wf[k] = (short)b;
            }
        }

        // reload slot s with chunk c+2 (stays in flight ~2 iterations; clamped tail re-read)
        const int cp = (c + 2 < NC) ? c + 2 : c;
        const int offp = cp * CK;
        aj[s][0] = *(const int4*)(pA + offp);
        aj[s][1] = *(const int4*)(pA + offp + 4);
        sd[s][0] = *(const float4*)(pD + offp);
        sd[s][1] = *(const float4*)(pD + offp + 4);

        // second half B loads (col-groups 4..7)
        short8 B1[4];
#pragma unroll
        for (int cg = 0; cg < 4; ++cg)
            B1[cg] = *(const short8*)(pB + (size_t)(cg + 4) * 16 * N + off);

        // MFMA: 8 independent accumulations
#pragma unroll
        for (int cg = 0; cg < 4; ++cg)
            acc[cg] = __builtin_amdgcn_mfma_f32_16x16x32_bf16(wf, B0[cg], acc[cg], 0, 0, 0);
#pragma unroll
        for (int cg = 0; cg < 4; ++cg)
            acc[cg + 4] = __builtin_amdgcn_mfma_f32_16x16x32_bf16(wf, B1[cg], acc[cg + 4], 0, 0, 0);
    }

    // store partials: D layout col=lane&15, row=quad*4+reg
    float* dst = pacc + (size_t)split * N * F;
#pragma unroll
    for (int cg = 0; cg < 8; ++cg) {
        const int col = cg * 16 + l16;
        const int r0 = i0 + quad * 4;
#pragma unroll
        for (int r = 0; r < 4; ++r)
            dst[(size_t)(r0 + r) * F + col] = acc[cg][r];
    }

    // row sums: reduce over quads (lanes sharing l16)
    rsum += __shfl_xor(rsum, 16);
    rsum += __shfl_xor(rsum, 32);
    if (L < 16) pS[(size_t)split * N + i0 + l16] = rsum;
}

// ---------------- K3: out = (sum_s pacc_s) / (sum_s pS_s) ----------------
__global__ __launch_bounds__(256) void finalize(float* __restrict__ out,
                                                const float* __restrict__ pacc,
                                                const float* __restrict__ pS) {
    const int idx = (blockIdx.x * 256 + threadIdx.x) * 4;
    const int i = idx >> 7;
    float s = 0.f;
#pragma unroll
    for (int k = 0; k < NS; ++k) s += pS[(size_t)k * N + i];
    float4 a = {0.f, 0.f, 0.f, 0.f};
#pragma unroll
    for (int k = 0; k < NS; ++k) {
        float4 v = *(const float4*)&pacc[(size_t)k * N * F + idx];
        a.x += v.x; a.y += v.y; a.z += v.z; a.w += v.w;
    }
    const float inv = 1.0f / s;
    float4 o = {a.x * inv, a.y * inv, a.z * inv, a.w * inv};
    *(float4*)&out[idx] = o;
}

extern "C" void kernel_launch(void* const* d_in, const int* in_sizes, int n_in,
                              void* d_out, int out_size, void* d_ws, size_t ws_size,
                              hipStream_t stream) {
    (void)in_sizes; (void)n_in; (void)out_size; (void)ws_size;
    const float* x   = (const float*)d_in[0];
    const int*   adj = (const int*)d_in[1];
    const float* W   = (const float*)d_in[2];
    const float* a   = (const float*)d_in[3];
    float* out = (float*)d_out;

    u16* hT     = (u16*)d_ws;                    // N*F bf16 (2 MB)
    float* ssrc = (float*)(hT + (size_t)N * F);  // N
    float* sdst = ssrc + N;                      // N
    float* pS   = sdst + N;                      // NS*N
    float* pacc = pS + (size_t)NS * N;           // NS*N*F fp32 (32 MB)

    gemm_h<<<N / 32, 256, 0, stream>>>(x, W, a, hT, ssrc, sdst);
    attn_mfma<<<dim3(N / 64, NS), 256, 0, stream>>>(adj, hT, ssrc, sdst, pacc, pS);
    finalize<<<(N * F / 4) / 256, 256, 0, stream>>>(out, pacc, pS);
}

// Round 4
// 414.762 us; speedup vs baseline: 1.2276x; 1.2276x over previous
//
#include <hip/hip_runtime.h>

#define N 8192
#define F 128
#define NS 4             // j-splits
#define JT (N / NS)      // 2048 j per block
#define CJ 64            // j per chunk
#define NC (JT / CJ)     // 32 chunks
#define TI 32            // i-rows per block
#define WT_STRIDE 72     // wt row stride in shorts (64 + 8 pad, 144B = 16B-aligned)
#define ALPHA 0.2f

typedef __attribute__((ext_vector_type(8))) short short8;
typedef __attribute__((ext_vector_type(4))) float f32x4;
typedef unsigned short u16;

__device__ __forceinline__ u16 f2bf(float f) {
    unsigned int u = __float_as_uint(f);
    u += 0x7fff + ((u >> 16) & 1);  // RNE; finite inputs
    return (u16)(u >> 16);
}
__device__ __forceinline__ float bf2f(u16 b) {
    return __uint_as_float(((unsigned int)b) << 16);
}
__device__ __forceinline__ float lrelu(float z) { return fmaxf(z, ALPHA * z); }

// async global->LDS, 16B per lane; lptr must be wave-uniform (HW: base + lane*16)
__device__ __forceinline__ void dma16(const void* g, void* l) {
    __builtin_amdgcn_global_load_lds((__attribute__((address_space(1))) void*)g,
                                     (__attribute__((address_space(3))) void*)l, 16, 0, 0);
}

// ---------------- K1: h = x@W ; emit hT (bf16, [feature][node]) + ssrc/sdst (fp32) ----------------
__global__ __launch_bounds__(256) void gemm_h(const float* __restrict__ x,
                                              const float* __restrict__ W,
                                              const float* __restrict__ aa,
                                              u16* __restrict__ hT,
                                              float* __restrict__ ssrc,
                                              float* __restrict__ sdst) {
    __shared__ float xs[32 * 128];
    __shared__ float Wsh[32 * 128];
    const int t = threadIdx.x;
    const int i0 = blockIdx.x * 32;
    const int c4 = (t & 31) * 4;
    const int r8 = t >> 5;

#pragma unroll
    for (int p = 0; p < 4; ++p) {
        int rr = p * 8 + r8;
        *(float4*)&xs[rr * 128 + c4] = *(const float4*)&x[(size_t)(i0 + rr) * 128 + c4];
    }

    const int tx = t & 31, ty = t >> 5;
    const int r0 = ty * 4, c0 = tx * 4;
    float acc[4][4] = {};

    for (int kc = 0; kc < 4; ++kc) {
        __syncthreads();
#pragma unroll
        for (int p = 0; p < 4; ++p) {
            int k = p * 8 + r8;
            *(float4*)&Wsh[k * 128 + c4] = *(const float4*)&W[(kc * 32 + k) * 128 + c4];
        }
        __syncthreads();
#pragma unroll 4
        for (int k = 0; k < 32; k += 4) {
            float xr[4][4];
#pragma unroll
            for (int rr = 0; rr < 4; ++rr)
                *(float4*)xr[rr] = *(const float4*)&xs[(r0 + rr) * 128 + kc * 32 + k];
#pragma unroll
            for (int kk = 0; kk < 4; ++kk) {
                float4 wv = *(const float4*)&Wsh[(k + kk) * 128 + c0];
#pragma unroll
                for (int rr = 0; rr < 4; ++rr) {
                    acc[rr][0] += xr[rr][kk] * wv.x;
                    acc[rr][1] += xr[rr][kk] * wv.y;
                    acc[rr][2] += xr[rr][kk] * wv.z;
                    acc[rr][3] += xr[rr][kk] * wv.w;
                }
            }
        }
    }

#pragma unroll
    for (int rr = 0; rr < 4; ++rr)
#pragma unroll
        for (int cc = 0; cc < 4; ++cc)
            hT[(size_t)(c0 + cc) * N + (i0 + r0 + rr)] = f2bf(acc[rr][cc]);

    float4 asv = *(const float4*)&aa[c0];
    float4 adv = *(const float4*)&aa[F + c0];
#pragma unroll
    for (int rr = 0; rr < 4; ++rr) {
        float vs = acc[rr][0] * asv.x + acc[rr][1] * asv.y + acc[rr][2] * asv.z + acc[rr][3] * asv.w;
        float vd = acc[rr][0] * adv.x + acc[rr][1] * adv.y + acc[rr][2] * adv.z + acc[rr][3] * adv.w;
#pragma unroll
        for (int off = 16; off >= 1; off >>= 1) {
            vs += __shfl_down(vs, off, 32);
            vd += __shfl_down(vd, off, 32);
        }
        if (tx == 0) {
            ssrc[i0 + r0 + rr] = vs;
            sdst[i0 + r0 + rr] = vd;
        }
    }
}

// ---------------- K2: attention. Coalesced adj->VGPR, hT->LDS DMA (dbuf), w via LDS transpose. ----------------
__global__ __launch_bounds__(256, 4) void attn_mfma(const int* __restrict__ adj,
                                                    const u16* __restrict__ hT,
                                                    const float* __restrict__ ssrc,
                                                    const float* __restrict__ sdst,
                                                    float* __restrict__ pacc,
                                                    float* __restrict__ pS) {
    __shared__ u16 bt[2][128 * CJ];     // 2 x 16 KB, hT tile [feat][j], j-slot XOR-swizzled
    __shared__ u16 wt[TI * WT_STRIDE];  // 4.6 KB, w tile [row][j]

    const int t = threadIdx.x;
    const int w = t >> 6, L = t & 63;
    const int quad = L >> 4, l16 = L & 15;
    const int i0 = blockIdx.x * TI;
    const int split = blockIdx.y;
    const int j0 = split * JT;

    // w-compute roles: thread -> rows (ar, 16+ar), cols ac..ac+3 within chunk
    const int ar = t >> 4;
    const int ac = (t & 15) * 4;
    const float s_i0 = ssrc[i0 + ar];
    const float s_i1 = ssrc[i0 + 16 + ar];
    const size_t arow0 = (size_t)(i0 + ar) * N;
    const size_t arow1 = (size_t)(i0 + 16 + ar) * N;

    // btile DMA roles: per round rp, feat = rp*32 + (t>>3); slot (t&7) holds j-block (t&7)^(feat&7)
    const int bf = t >> 3;
    const int bsj = (t & 7) ^ (bf & 7);
    const size_t bgoff = (size_t)bf * N + j0 + bsj * 8;  // + rp*32*N + c*CJ

    // MFMA roles
    const int rt = w & 1;
    const int colbase = (w >> 1) * 4;

    f32x4 acc[4];
#pragma unroll
    for (int ci = 0; ci < 4; ++ci) acc[ci] = 0.f;
    float sum0 = 0.f, sum1 = 0.f;

    // prologue: issue bt(0) DMA; load adj/sdst(0) into regs
#pragma unroll
    for (int rp = 0; rp < 4; ++rp)
        dma16(hT + bgoff + (size_t)rp * 32 * N, &bt[0][rp * 2048 + w * 512]);
    int4 a0 = *(const int4*)(adj + arow0 + j0 + ac);
    int4 a1 = *(const int4*)(adj + arow1 + j0 + ac);
    float4 dv = *(const float4*)(sdst + j0 + ac);

    for (int c = 0; c < NC; ++c) {
        // ---- w-compute(c) from regs (no barrier between adj load and here) ----
        ushort4 wlo, whi;
        {
            int m0[4] = {a0.x, a0.y, a0.z, a0.w};
            int m1[4] = {a1.x, a1.y, a1.z, a1.w};
            float d[4] = {dv.x, dv.y, dv.z, dv.w};
            u16 q0[4], q1[4];
#pragma unroll
            for (int k = 0; k < 4; ++k) {
                float e0 = __expf(lrelu(s_i0 + d[k]));
                float e1 = __expf(lrelu(s_i1 + d[k]));
                q0[k] = f2bf(m0[k] > 0 ? e0 : 0.f);
                q1[k] = f2bf(m1[k] > 0 ? e1 : 0.f);
                sum0 += bf2f(q0[k]);
                sum1 += bf2f(q1[k]);
            }
            wlo = {q0[0], q0[1], q0[2], q0[3]};
            whi = {q1[0], q1[1], q1[2], q1[3]};
        }

        __syncthreads();  // barrA: MFMA(c-1) LDS reads done; drains bt(c) DMA (cover: MFMA(c-1)+w-compute(c))
        *(ushort4*)&wt[ar * WT_STRIDE + ac] = wlo;
        *(ushort4*)&wt[(16 + ar) * WT_STRIDE + ac] = whi;
        __syncthreads();  // barrB: wt visible; cheap (no vmem outstanding)

        // issue bt(c+1) DMA + adj/sdst(c+1) loads; drained/consumed after a full MFMA phase
        const int cn = (c + 1 < NC) ? c + 1 : c;
        const size_t jn = (size_t)cn * CJ;
        {
            u16* dstb = bt[(c + 1) & 1];
#pragma unroll
            for (int rp = 0; rp < 4; ++rp)
                dma16(hT + bgoff + (size_t)rp * 32 * N + jn, &dstb[rp * 2048 + w * 512]);
        }
        a0 = *(const int4*)(adj + arow0 + j0 + jn + ac);
        a1 = *(const int4*)(adj + arow1 + j0 + jn + ac);
        dv = *(const float4*)(sdst + j0 + jn + ac);

        // ---- MFMA(c): A from wt, B from bt[c&1] ----
        const u16* btc = bt[c & 1];
#pragma unroll
        for (int ks = 0; ks < 2; ++ks) {
            short8 A = *(const short8*)&wt[(rt * 16 + l16) * WT_STRIDE + ks * 32 + quad * 8];
#pragma unroll
            for (int ci = 0; ci < 4; ++ci) {
                const int f = (colbase + ci) * 16 + l16;
                const int s = (ks * 4 + quad) ^ (f & 7);
                short8 B = *(const short8*)&btc[(f >> 5) * 2048 + (f & 31) * 64 + s * 8];
                acc[ci] = __builtin_amdgcn_mfma_f32_16x16x32_bf16(A, B, acc[ci], 0, 0, 0);
            }
        }
    }

    // store partials: D layout col=lane&15, row=quad*4+reg
    float* dst = pacc + (size_t)split * N * F;
#pragma unroll
    for (int ci = 0; ci < 4; ++ci) {
        const int col = (colbase + ci) * 16 + l16;
        const int r0 = i0 + rt * 16 + quad * 4;
#pragma unroll
        for (int r = 0; r < 4; ++r)
            dst[(size_t)(r0 + r) * F + col] = acc[ci][r];
    }

    // row sums: reduce across the 16 lanes sharing ar
#pragma unroll
    for (int off = 8; off >= 1; off >>= 1) {
        sum0 += __shfl_down(sum0, off, 16);
        sum1 += __shfl_down(sum1, off, 16);
    }
    if ((t & 15) == 0) {
        pS[(size_t)split * N + i0 + ar] = sum0;
        pS[(size_t)split * N + i0 + 16 + ar] = sum1;
    }
}

// ---------------- K3: out = (sum_s pacc_s) / (sum_s pS_s) ----------------
__global__ __launch_bounds__(256) void finalize(float* __restrict__ out,
                                                const float* __restrict__ pacc,
                                                const float* __restrict__ pS) {
    const int idx = (blockIdx.x * 256 + threadIdx.x) * 4;
    const int i = idx >> 7;
    float s = 0.f;
#pragma unroll
    for (int k = 0; k < NS; ++k) s += pS[(size_t)k * N + i];
    float4 a = {0.f, 0.f, 0.f, 0.f};
#pragma unroll
    for (int k = 0; k < NS; ++k) {
        float4 v = *(const float4*)&pacc[(size_t)k * N * F + idx];
        a.x += v.x; a.y += v.y; a.z += v.z; a.w += v.w;
    }
    const float inv = 1.0f / s;
    float4 o = {a.x * inv, a.y * inv, a.z * inv, a.w * inv};
    *(float4*)&out[idx] = o;
}

extern "C" void kernel_launch(void* const* d_in, const int* in_sizes, int n_in,
                              void* d_out, int out_size, void* d_ws, size_t ws_size,
                              hipStream_t stream) {
    (void)in_sizes; (void)n_in; (void)out_size; (void)ws_size;
    const float* x   = (const float*)d_in[0];
    const int*   adj = (const int*)d_in[1];
    const float* W   = (const float*)d_in[2];
    const float* a   = (const float*)d_in[3];
    float* out = (float*)d_out;

    u16* hT     = (u16*)d_ws;                    // N*F bf16 (2 MB)
    float* ssrc = (float*)(hT + (size_t)N * F);  // N
    float* sdst = ssrc + N;                      // N
    float* pS   = sdst + N;                      // NS*N
    float* pacc = pS + (size_t)NS * N;           // NS*N*F fp32 (16 MB)

    gemm_h<<<N / 32, 256, 0, stream>>>(x, W, a, hT, ssrc, sdst);
    attn_mfma<<<dim3(N / TI, NS), 256, 0, stream>>>(adj, hT, ssrc, sdst, pacc, pS);
    finalize<<<(N * F / 4) / 256, 256, 0, stream>>>(out, pacc, pS);
}